// Round 9
// baseline (882.873 us; speedup 1.0000x reference)
//
#include <hip/hip_runtime.h>
#include <hip/hip_bf16.h>

#define N_NODES 131072
#define N_EDGES 524288
#define F_IN 16
#define DIM 64
#define DNN 16
#define BK 4
#define NG 8192
#define N_ITERS 8   // NL1*NL2

typedef __bf16 bf16x8 __attribute__((ext_vector_type(8)));
typedef float f32x4 __attribute__((ext_vector_type(4)));

#define FMA4(A_, S_, W_) { (A_).x = fmaf((S_), (W_).x, (A_).x); (A_).y = fmaf((S_), (W_).y, (A_).y); \
                           (A_).z = fmaf((S_), (W_).z, (A_).z); (A_).w = fmaf((S_), (W_).w, (A_).w); }

// ---------------- degree (int) ----------------
__global__ __launch_bounds__(256) void k_degree(const int* __restrict__ ei, int* __restrict__ cnt) {
    int e = blockIdx.x * 256 + threadIdx.x;
    atomicAdd(&cnt[ei[N_EDGES + e]], 1);
}

__global__ __launch_bounds__(256) void k_invcnt(const int* __restrict__ cnt, float* __restrict__ inv) {
    int i = blockIdx.x * 256 + threadIdx.x;
    inv[i] = 1.0f / (float)max(cnt[i], 1);
}

// ---------------- CSR scan: per-block exclusive scan + block sums ----------------
__global__ __launch_bounds__(256) void k_scanA(const int* __restrict__ cnt, int* __restrict__ excl,
                                               int* __restrict__ bsum) {
    __shared__ int a[256], b[256];
    int t = threadIdx.x, gid = blockIdx.x * 256 + t;
    int c = cnt[gid];
    a[t] = c; __syncthreads();
    int *s = a, *d = b;
#pragma unroll
    for (int off = 1; off < 256; off <<= 1) {
        d[t] = s[t] + (t >= off ? s[t - off] : 0);
        __syncthreads();
        int* tmp = s; s = d; d = tmp;
    }
    excl[gid] = s[t] - c;
    if (t == 255) bsum[blockIdx.x] = s[255];
}

__global__ __launch_bounds__(256) void k_scanB(const int* __restrict__ bsum, int* __restrict__ boff) {
    __shared__ int a[512], b[512];
    int t = threadIdx.x;
    a[t] = bsum[t]; a[t + 256] = bsum[t + 256];
    __syncthreads();
    int *s = a, *d = b;
#pragma unroll
    for (int off = 1; off < 512; off <<= 1) {
        d[t] = s[t] + (t >= off ? s[t - off] : 0);
        int i2 = t + 256;
        d[i2] = s[i2] + (i2 >= off ? s[i2 - off] : 0);
        __syncthreads();
        int* tmp = s; s = d; d = tmp;
    }
    boff[t] = t ? s[t - 1] : 0;
    boff[t + 256] = s[t + 255];
}

__global__ __launch_bounds__(256) void k_scanC(const int* __restrict__ excl, const int* __restrict__ boff,
                                               int* __restrict__ row_ptr, int* __restrict__ cursor) {
    int gid = blockIdx.x * 256 + threadIdx.x;
    int v = excl[gid] + boff[gid >> 8];
    row_ptr[gid] = v;
    cursor[gid] = v;
    if (gid == 0) row_ptr[N_NODES] = N_EDGES;
}

__global__ __launch_bounds__(256) void k_scatter(const int* __restrict__ ei, const float* __restrict__ ea,
                                                 int* __restrict__ cursor, int* __restrict__ csr_src,
                                                 float4* __restrict__ csr_ea) {
    int e = blockIdx.x * 256 + threadIdx.x;
    int dst = ei[N_EDGES + e];
    int pos = atomicAdd(&cursor[dst], 1);
    csr_src[pos] = ei[e];
    csr_ea[pos] = ((const float4*)ea)[e];
}

// ---------------- prep: build bf16 B-fragment weight tiles ----------------
__global__ __launch_bounds__(256) void k_prep(const float* __restrict__ wih, const float* __restrict__ whh,
                                              const float* __restrict__ rw, const float* __restrict__ w1,
                                              const float* __restrict__ bih, const float* __restrict__ bhh,
                                              __bf16* __restrict__ Wb, __bf16* __restrict__ rwb,
                                              __bf16* __restrict__ w1b) {
    int idx = blockIdx.x * 256 + threadIdx.x;
    if (idx < 4 * 40 * 512) {
        int j = idx / 20480, r = idx % 20480;
        int t = r >> 9, e = r & 511;
        int jj = e & 7, c16 = (e >> 3) & 15, kq = e >> 7;
        int ct, kk; bool nih = false;
        if (t < 36) { ct = t / 3; kk = t % 3; } else { ct = 8 + (t - 36); kk = 0; nih = true; }
        int k = kk * 32 + kq * 8 + jj;
        int c = ct * 16 + c16;
        bool ngate = ct >= 8;
        float v = 0.f;
        if (nih) {
            if (k < 16) v = wih[((size_t)j * 192 + c) * 16 + k];
        } else {
            if (k < 16) v = ngate ? 0.f : wih[((size_t)j * 192 + c) * 16 + k];
            else if (k < 80) v = whh[((size_t)j * 192 + c) * 64 + (k - 16)];
            else if (k == 80) v = ngate ? bhh[j * 192 + c] : (bih[j * 192 + c] + bhh[j * 192 + c]);
        }
        Wb[idx] = (__bf16)v;
    } else if (idx < 4 * 40 * 512 + 512) {
        int e = idx - 4 * 40 * 512;
        int jj = e & 7, c16 = (e >> 3) & 15, kq = e >> 7;
        int k = kq * 8 + jj;
        rwb[e] = (__bf16)((k < 16) ? rw[k * 16 + c16] : 0.f);
    } else if (idx < 4 * 40 * 512 + 512 + 1024) {
        int e = idx - (4 * 40 * 512 + 512);
        int t2 = e >> 9, ee = e & 511;
        int jj = ee & 7, c16 = (ee >> 3) & 15, kq = ee >> 7;
        int k = t2 * 32 + kq * 8 + jj;
        w1b[e] = (__bf16)w1[k * 16 + c16];
    }
}

// ---------------- init: h = relu(x @ lin0_w + lin0_b), 4 channels/thread ----------------
__global__ __launch_bounds__(256) void k_init(const float* __restrict__ x, const float* __restrict__ w,
                                              const float* __restrict__ b, float* __restrict__ h) {
    __shared__ float s_w[F_IN * DIM];
    int tid = threadIdx.x;
    for (int i = tid; i < F_IN * DIM; i += 256) s_w[i] = w[i];
    int node = blockIdx.x * 16 + (tid >> 4);
    int c4 = tid & 15;                   // channels 4*c4 .. 4*c4+3
    const float4* xp = (const float4*)(x + (size_t)node * F_IN);
    float4 x0 = xp[0], x1 = xp[1], x2 = xp[2], x3 = xp[3];
    float xa[16] = {x0.x, x0.y, x0.z, x0.w, x1.x, x1.y, x1.z, x1.w,
                    x2.x, x2.y, x2.z, x2.w, x3.x, x3.y, x3.z, x3.w};
    __syncthreads();
    float4 acc = ((const float4*)b)[c4];
    const float4* w4 = (const float4*)s_w;
#pragma unroll
    for (int k = 0; k < 16; ++k) {
        float4 wv = w4[k * 16 + c4];
        FMA4(acc, xa[k], wv);
    }
    acc.x = fmaxf(acc.x, 0.f); acc.y = fmaxf(acc.y, 0.f);
    acc.z = fmaxf(acc.z, 0.f); acc.w = fmaxf(acc.w, 0.f);
    *(float4*)(h + (size_t)node * DIM + c4 * 4) = acc;
}

// ---------------- out1 = h @ lin1_w + lin1_b (once, pre-loop) ----------------
__global__ __launch_bounds__(256) void k_lin1(const float* __restrict__ h, const float* __restrict__ w,
                                              const float* __restrict__ b, float* __restrict__ out1) {
    __shared__ float s_h[64 * 68];
    int tid = threadIdx.x;
    int nb = blockIdx.x * 64;
    const float4* hp = (const float4*)(h + (size_t)nb * 64);
    for (int i = tid; i < 64 * 16; i += 256) {
        int n = i >> 4, q4 = i & 15;
        float4 v = hp[i];
        *(float4*)&s_h[n * 68 + q4 * 4] = v;
    }
    int ct = tid & 15;
    float wcol[64];
#pragma unroll
    for (int q = 0; q < 64; ++q) wcol[q] = w[q * 16 + ct];
    float bias = b[ct];
    __syncthreads();
    int ng = tid >> 4;
#pragma unroll
    for (int rep = 0; rep < 4; ++rep) {
        int nl = ng + 16 * rep;
        float acc = bias;
#pragma unroll
        for (int q4 = 0; q4 < 16; ++q4) {
            float4 hv = *(const float4*)&s_h[nl * 68 + q4 * 4];
            acc = fmaf(hv.x, wcol[4 * q4 + 0], acc);
            acc = fmaf(hv.y, wcol[4 * q4 + 1], acc);
            acc = fmaf(hv.z, wcol[4 * q4 + 2], acc);
            acc = fmaf(hv.w, wcol[4 * q4 + 3], acc);
        }
        out1[(size_t)(nb + nl) * 16 + ct] = acc;
    }
}

// ---------------- aggr: CSR gather-mean, no atomics ----------------
// 16 lanes per dst node; W_e recomputed per edge; aggr = segsum * inv_cnt
__attribute__((amdgpu_waves_per_eu(2, 4)))
__global__ __launch_bounds__(256) void k_aggr(const float* __restrict__ out1, const int* __restrict__ csr_src,
                                              const float4* __restrict__ csr_ea, const int* __restrict__ row_ptr,
                                              const float* __restrict__ inv_cnt, const float* __restrict__ nn1w,
                                              const float* __restrict__ nn1b, float* __restrict__ aggr) {
    int tid = threadIdx.x;
    int o = tid & 15;
    float w0[16], w1[16], w2[16], w3[16], bs[16];
#pragma unroll
    for (int k = 0; k < 16; ++k) {
        int wi = k * 16 + o;
        bs[k] = nn1b[wi];
        w0[k] = nn1w[wi];
        w1[k] = nn1w[256 + wi];
        w2[k] = nn1w[512 + wi];
        w3[k] = nn1w[768 + wi];
    }
    int n = blockIdx.x * 16 + (tid >> 4);
    int e0 = row_ptr[n], e1 = row_ptr[n + 1];
    float acc = 0.f;
    for (int e = e0; e < e1; ++e) {
        int src = csr_src[e];
        float4 a = csr_ea[e];
        const float4* xp = (const float4*)(out1 + (size_t)src * 16);
        float4 x0 = xp[0], x1 = xp[1], x2 = xp[2], x3 = xp[3];
        float xa[16] = {x0.x, x0.y, x0.z, x0.w, x1.x, x1.y, x1.z, x1.w,
                        x2.x, x2.y, x2.z, x2.w, x3.x, x3.y, x3.z, x3.w};
        float msg = 0.f;
#pragma unroll
        for (int k = 0; k < 16; ++k) {
            float wv = bs[k];
            wv = fmaf(a.x, w0[k], wv);
            wv = fmaf(a.y, w1[k], wv);
            wv = fmaf(a.z, w2[k], wv);
            wv = fmaf(a.w, w3[k], wv);
            msg = fmaf(xa[k], wv, msg);
        }
        acc += msg;
    }
    aggr[(size_t)n * 16 + o] = acc * inv_cnt[n];
}

// ---------------- node: MFMA GRU (aggr is already the mean; no zeroing) ----------------
__attribute__((amdgpu_waves_per_eu(2)))
__global__ __launch_bounds__(256) void k_node(
    float* __restrict__ out1, const float* __restrict__ aggr,
    float* __restrict__ h, const __bf16* __restrict__ Wb, const __bf16* __restrict__ rwb,
    const __bf16* __restrict__ w1b, const float* __restrict__ conv_b,
    const float* __restrict__ bih, const float* __restrict__ lin1_b)
{
    __shared__ __align__(16) __bf16 s_X[64 * 104];   // 13312 B
    __shared__ __align__(16) __bf16 s_W[40 * 512];   // 40960 B
    __shared__ __align__(16) __bf16 s_rw[512];
    __shared__ __align__(16) __bf16 s_w1[1024];
    int tid = threadIdx.x;
    int nb = blockIdx.x * 64;
    int lane = tid & 63, w = tid >> 6;
    int c16 = lane & 15, lq = lane >> 4;

    {
        const float4* src = (const float4*)Wb;
        float4* dst = (float4*)s_W;
#pragma unroll
        for (int i = 0; i < 10; ++i) dst[tid + 256 * i] = src[tid + 256 * i];
        if (tid < 64) ((float4*)s_rw)[tid] = ((const float4*)rwb)[tid];
        else if (tid < 192) ((float4*)s_w1)[tid - 64] = ((const float4*)w1b)[tid - 64];
    }
    {
        const float4* hsrc = (const float4*)(h + (size_t)nb * 64);
#pragma unroll
        for (int ii = 0; ii < 4; ++ii) {
            int i = tid + 256 * ii;
            float4 v = hsrc[i];
            int n = i >> 4, d4 = i & 15;
            __bf16* p = &s_X[n * 104 + 16 + d4 * 4];
            p[0] = (__bf16)v.x; p[1] = (__bf16)v.y; p[2] = (__bf16)v.z; p[3] = (__bf16)v.w;
        }
    }
    {
        float4 v = ((const float4*)(out1 + (size_t)nb * 16))[tid];
        int n = tid >> 2, k4 = tid & 3;
        __bf16* p = &s_X[n * 104 + k4 * 4];
        p[0] = (__bf16)v.x; p[1] = (__bf16)v.y; p[2] = (__bf16)v.z; p[3] = (__bf16)v.w;
        int c2 = (tid & 3) * 6;
#pragma unroll
        for (int q = 0; q < 6; ++q) {
            int col = 80 + c2 + q;
            s_X[n * 104 + col] = (col == 80) ? (__bf16)1.0f : (__bf16)0.0f;
        }
    }
    __syncthreads();

    // o2 = out1 @ root_w + aggr + conv_b
    f32x4 co2;
    {
        float cb = conv_b[c16];
#pragma unroll
        for (int jr = 0; jr < 4; ++jr) {
            int node = nb + w * 16 + 4 * lq + jr;
            co2[jr] = aggr[(size_t)node * 16 + c16] + cb;
        }
        bf16x8 a0 = *(const bf16x8*)&s_X[(w * 16 + c16) * 104 + lq * 8];
        bf16x8 brw = *(const bf16x8*)&s_rw[lane * 8];
        co2 = __builtin_amdgcn_mfma_f32_16x16x32_bf16(a0, brw, co2, 0, 0, 0);
    }
    __syncthreads();
    {
#pragma unroll
        for (int jr = 0; jr < 4; ++jr)
            s_X[(w * 16 + 4 * lq + jr) * 104 + c16] = (__bf16)co2[jr];
    }
    __syncthreads();

    // gates GEMM
    f32x4 acc[12], ani4[4];
#pragma unroll
    for (int i = 0; i < 12; ++i) acc[i] = (f32x4){0.f, 0.f, 0.f, 0.f};
#pragma unroll
    for (int i = 0; i < 4; ++i) ani4[i] = (f32x4){0.f, 0.f, 0.f, 0.f};
    bf16x8 af[3];
#pragma unroll
    for (int kk = 0; kk < 3; ++kk)
        af[kk] = *(const bf16x8*)&s_X[(w * 16 + c16) * 104 + kk * 32 + lq * 8];
#pragma unroll
    for (int ct = 0; ct < 12; ++ct) {
#pragma unroll
        for (int kk = 0; kk < 3; ++kk) {
            bf16x8 bf = *(const bf16x8*)&s_W[(ct * 3 + kk) * 512 + lane * 8];
            acc[ct] = __builtin_amdgcn_mfma_f32_16x16x32_bf16(af[kk], bf, acc[ct], 0, 0, 0);
        }
    }
#pragma unroll
    for (int ct8 = 0; ct8 < 4; ++ct8) {
        bf16x8 bf = *(const bf16x8*)&s_W[(36 + ct8) * 512 + lane * 8];
        ani4[ct8] = __builtin_amdgcn_mfma_f32_16x16x32_bf16(af[0], bf, ani4[ct8], 0, 0, 0);
    }

    // epilogue
    float hn[4][4];
#pragma unroll
    for (int ct = 0; ct < 4; ++ct) {
        float bni = bih[128 + ct * 16 + c16];
#pragma unroll
        for (int jr = 0; jr < 4; ++jr) {
            int node = nb + w * 16 + 4 * lq + jr;
            float hold = h[(size_t)node * 64 + ct * 16 + c16];
            float rr = 1.f / (1.f + __expf(-acc[ct][jr]));
            float zz = 1.f / (1.f + __expf(-acc[4 + ct][jr]));
            float xx = fmaf(rr, acc[8 + ct][jr], ani4[ct][jr] + bni);
            float ax = fabsf(xx);
            float ee = __expf(-2.f * ax);
            float ncv = __builtin_copysignf((1.f - ee) / (1.f + ee), xx);
            float hv = fmaf(zz, hold - ncv, ncv);
            hn[ct][jr] = hv;
            h[(size_t)node * 64 + ct * 16 + c16] = hv;
        }
    }
    __syncthreads();
#pragma unroll
    for (int ct = 0; ct < 4; ++ct)
#pragma unroll
        for (int jr = 0; jr < 4; ++jr)
            s_X[(w * 16 + 4 * lq + jr) * 104 + 16 + ct * 16 + c16] = (__bf16)hn[ct][jr];
    __syncthreads();

    // fused lin1
    f32x4 o1acc = (f32x4){0.f, 0.f, 0.f, 0.f};
#pragma unroll
    for (int kk = 0; kk < 2; ++kk) {
        bf16x8 a = *(const bf16x8*)&s_X[(w * 16 + c16) * 104 + 16 + kk * 32 + lq * 8];
        bf16x8 b = *(const bf16x8*)&s_w1[kk * 512 + lane * 8];
        o1acc = __builtin_amdgcn_mfma_f32_16x16x32_bf16(a, b, o1acc, 0, 0, 0);
    }
    float lb = lin1_b[c16];
#pragma unroll
    for (int jr = 0; jr < 4; ++jr) {
        int node = nb + w * 16 + 4 * lq + jr;
        out1[(size_t)node * 16 + c16] = o1acc[jr] + lb;
    }
}

// ---------------- final ----------------
__global__ __launch_bounds__(256) void k_final(const float* __restrict__ h, const float* __restrict__ w2,
                                               const int* __restrict__ batch, float* __restrict__ out) {
    int i = blockIdx.x * 4 + (threadIdx.x >> 6);
    int lane = threadIdx.x & 63;
    float v = h[(size_t)i * DIM + lane] * w2[lane];
#pragma unroll
    for (int off = 32; off > 0; off >>= 1) v += __shfl_down(v, off, 64);
    if (lane == 0) atomicAdd(&out[batch[i]], v);
}

extern "C" void kernel_launch(void* const* d_in, const int* in_sizes, int n_in,
                              void* d_out, int out_size, void* d_ws, size_t ws_size,
                              hipStream_t stream) {
    const float* x        = (const float*)d_in[0];
    const float* edge_attr= (const float*)d_in[1];
    const float* lin0_w   = (const float*)d_in[2];
    const float* lin0_b   = (const float*)d_in[3];
    const float* nn1_w    = (const float*)d_in[4];
    const float* nn1_b    = (const float*)d_in[5];
    const float* root_w   = (const float*)d_in[6];
    const float* conv_b   = (const float*)d_in[7];
    const float* gru_w_ih = (const float*)d_in[8];
    const float* gru_w_hh = (const float*)d_in[9];
    const float* gru_b_ih = (const float*)d_in[10];
    const float* gru_b_hh = (const float*)d_in[11];
    const float* lin1_w   = (const float*)d_in[12];
    const float* lin1_b   = (const float*)d_in[13];
    const float* lin2_w   = (const float*)d_in[14];
    const int*   ei       = (const int*)d_in[15];
    const int*   batch    = (const int*)d_in[16];
    float* out = (float*)d_out;

    char* p = (char*)d_ws;
    float*  h       = (float*)p;            p += (size_t)N_NODES * DIM * 4;
    float*  out1    = (float*)p;            p += (size_t)N_NODES * DNN * 4;
    float*  aggr    = (float*)p;            p += (size_t)N_NODES * DNN * 4;
    float4* csr_ea  = (float4*)p;           p += (size_t)N_EDGES * 16;
    __bf16* Wb      = (__bf16*)p;           p += 4 * 40 * 512 * 2;
    __bf16* rwb     = (__bf16*)p;           p += 512 * 2;
    __bf16* w1b     = (__bf16*)p;           p += 1024 * 2;
    int*    cnt     = (int*)p;              p += (size_t)N_NODES * 4;
    float*  inv_cnt = (float*)p;            p += (size_t)N_NODES * 4;
    int*    row_ptr = (int*)p;              p += (size_t)(N_NODES + 16) * 4;
    int*    cursor  = (int*)p;              p += (size_t)N_NODES * 4;
    int*    excl    = (int*)p;              p += (size_t)N_NODES * 4;
    int*    bsum    = (int*)p;              p += 512 * 4;
    int*    boff    = (int*)p;              p += 512 * 4;
    int*    csr_src = (int*)p;              p += (size_t)N_EDGES * 4;

    hipMemsetAsync(d_out, 0, (size_t)NG * 4, stream);
    hipMemsetAsync(cnt, 0, (size_t)N_NODES * 4, stream);
    k_prep<<<326, 256, 0, stream>>>(gru_w_ih, gru_w_hh, root_w, lin1_w, gru_b_ih, gru_b_hh,
                                    Wb, rwb, w1b);
    k_degree<<<N_EDGES / 256, 256, 0, stream>>>(ei, cnt);
    k_scanA<<<N_NODES / 256, 256, 0, stream>>>(cnt, excl, bsum);
    k_scanB<<<1, 256, 0, stream>>>(bsum, boff);
    k_scanC<<<N_NODES / 256, 256, 0, stream>>>(excl, boff, row_ptr, cursor);
    k_scatter<<<N_EDGES / 256, 256, 0, stream>>>(ei, edge_attr, cursor, csr_src, csr_ea);
    k_invcnt<<<N_NODES / 256, 256, 0, stream>>>(cnt, inv_cnt);
    k_init<<<N_NODES / 16, 256, 0, stream>>>(x, lin0_w, lin0_b, h);
    k_lin1<<<N_NODES / 64, 256, 0, stream>>>(h, lin1_w, lin1_b, out1);

    for (int it = 0; it < N_ITERS; ++it) {
        int j = it >> 1;   // GRU index (NL2 = 2)
        k_aggr<<<N_NODES / 16, 256, 0, stream>>>(out1, csr_src, csr_ea, row_ptr, inv_cnt,
                                                 nn1_w, nn1_b, aggr);
        k_node<<<N_NODES / 64, 256, 0, stream>>>(out1, aggr, h,
                                                 Wb + (size_t)j * 40 * 512, rwb, w1b,
                                                 conv_b, gru_b_ih + (size_t)j * 192, lin1_b);
    }
    k_final<<<N_NODES / 4, 256, 0, stream>>>(h, lin2_w, batch, out);
}

// Round 10
// 826.785 us; speedup vs baseline: 1.0678x; 1.0678x over previous
//
#include <hip/hip_runtime.h>
#include <hip/hip_bf16.h>

#define N_NODES 131072
#define N_EDGES 524288
#define F_IN 16
#define DIM 64
#define DNN 16
#define BK 4
#define NG 8192
#define N_ITERS 8   // NL1*NL2

typedef __bf16 bf16x8 __attribute__((ext_vector_type(8)));
typedef float f32x4 __attribute__((ext_vector_type(4)));

#define FMA4(A_, S_, W_) { (A_).x = fmaf((S_), (W_).x, (A_).x); (A_).y = fmaf((S_), (W_).y, (A_).y); \
                           (A_).z = fmaf((S_), (W_).z, (A_).z); (A_).w = fmaf((S_), (W_).w, (A_).w); }

// ---------------- degree (int) ----------------
__global__ __launch_bounds__(256) void k_degree(const int* __restrict__ ei, int* __restrict__ cnt) {
    int e = blockIdx.x * 256 + threadIdx.x;
    atomicAdd(&cnt[ei[N_EDGES + e]], 1);
}

__global__ __launch_bounds__(256) void k_invcnt(const int* __restrict__ cnt, float* __restrict__ inv) {
    int i = blockIdx.x * 256 + threadIdx.x;
    inv[i] = 1.0f / (float)max(cnt[i], 1);
}

// ---------------- CSR scan ----------------
__global__ __launch_bounds__(256) void k_scanA(const int* __restrict__ cnt, int* __restrict__ excl,
                                               int* __restrict__ bsum) {
    __shared__ int a[256], b[256];
    int t = threadIdx.x, gid = blockIdx.x * 256 + t;
    int c = cnt[gid];
    a[t] = c; __syncthreads();
    int *s = a, *d = b;
#pragma unroll
    for (int off = 1; off < 256; off <<= 1) {
        d[t] = s[t] + (t >= off ? s[t - off] : 0);
        __syncthreads();
        int* tmp = s; s = d; d = tmp;
    }
    excl[gid] = s[t] - c;
    if (t == 255) bsum[blockIdx.x] = s[255];
}

__global__ __launch_bounds__(256) void k_scanB(const int* __restrict__ bsum, int* __restrict__ boff) {
    __shared__ int a[512], b[512];
    int t = threadIdx.x;
    a[t] = bsum[t]; a[t + 256] = bsum[t + 256];
    __syncthreads();
    int *s = a, *d = b;
#pragma unroll
    for (int off = 1; off < 512; off <<= 1) {
        d[t] = s[t] + (t >= off ? s[t - off] : 0);
        int i2 = t + 256;
        d[i2] = s[i2] + (i2 >= off ? s[i2 - off] : 0);
        __syncthreads();
        int* tmp = s; s = d; d = tmp;
    }
    boff[t] = t ? s[t - 1] : 0;
    boff[t + 256] = s[t + 255];
}

__global__ __launch_bounds__(256) void k_scanC(const int* __restrict__ excl, const int* __restrict__ boff,
                                               int* __restrict__ row_ptr, int* __restrict__ cursor) {
    int gid = blockIdx.x * 256 + threadIdx.x;
    int v = excl[gid] + boff[gid >> 8];
    row_ptr[gid] = v;
    cursor[gid] = v;
    if (gid == 0) row_ptr[N_NODES] = N_EDGES;
}

__global__ __launch_bounds__(256) void k_scatter(const int* __restrict__ ei, const float* __restrict__ ea,
                                                 int* __restrict__ cursor, int* __restrict__ csr_src,
                                                 float4* __restrict__ csr_ea) {
    int e = blockIdx.x * 256 + threadIdx.x;
    int dst = ei[N_EDGES + e];
    int pos = atomicAdd(&cursor[dst], 1);
    csr_src[pos] = ei[e];
    csr_ea[pos] = ((const float4*)ea)[e];
}

// ---------------- prep: build bf16 B-fragment weight tiles ----------------
__global__ __launch_bounds__(256) void k_prep(const float* __restrict__ wih, const float* __restrict__ whh,
                                              const float* __restrict__ rw, const float* __restrict__ w1,
                                              const float* __restrict__ bih, const float* __restrict__ bhh,
                                              __bf16* __restrict__ Wb, __bf16* __restrict__ rwb,
                                              __bf16* __restrict__ w1b) {
    int idx = blockIdx.x * 256 + threadIdx.x;
    if (idx < 4 * 40 * 512) {
        int j = idx / 20480, r = idx % 20480;
        int t = r >> 9, e = r & 511;
        int jj = e & 7, c16 = (e >> 3) & 15, kq = e >> 7;
        int ct, kk; bool nih = false;
        if (t < 36) { ct = t / 3; kk = t % 3; } else { ct = 8 + (t - 36); kk = 0; nih = true; }
        int k = kk * 32 + kq * 8 + jj;
        int c = ct * 16 + c16;
        bool ngate = ct >= 8;
        float v = 0.f;
        if (nih) {
            if (k < 16) v = wih[((size_t)j * 192 + c) * 16 + k];
        } else {
            if (k < 16) v = ngate ? 0.f : wih[((size_t)j * 192 + c) * 16 + k];
            else if (k < 80) v = whh[((size_t)j * 192 + c) * 64 + (k - 16)];
            else if (k == 80) v = ngate ? bhh[j * 192 + c] : (bih[j * 192 + c] + bhh[j * 192 + c]);
        }
        Wb[idx] = (__bf16)v;
    } else if (idx < 4 * 40 * 512 + 512) {
        int e = idx - 4 * 40 * 512;
        int jj = e & 7, c16 = (e >> 3) & 15, kq = e >> 7;
        int k = kq * 8 + jj;
        rwb[e] = (__bf16)((k < 16) ? rw[k * 16 + c16] : 0.f);
    } else if (idx < 4 * 40 * 512 + 512 + 1024) {
        int e = idx - (4 * 40 * 512 + 512);
        int t2 = e >> 9, ee = e & 511;
        int jj = ee & 7, c16 = (ee >> 3) & 15, kq = ee >> 7;
        int k = t2 * 32 + kq * 8 + jj;
        w1b[e] = (__bf16)w1[k * 16 + c16];
    }
}

// ---------------- init: h = relu(x @ lin0_w + lin0_b), 4 channels/thread ----------------
__global__ __launch_bounds__(256) void k_init(const float* __restrict__ x, const float* __restrict__ w,
                                              const float* __restrict__ b, float* __restrict__ h) {
    __shared__ float s_w[F_IN * DIM];
    int tid = threadIdx.x;
    for (int i = tid; i < F_IN * DIM; i += 256) s_w[i] = w[i];
    int node = blockIdx.x * 16 + (tid >> 4);
    int c4 = tid & 15;
    const float4* xp = (const float4*)(x + (size_t)node * F_IN);
    float4 x0 = xp[0], x1 = xp[1], x2 = xp[2], x3 = xp[3];
    float xa[16] = {x0.x, x0.y, x0.z, x0.w, x1.x, x1.y, x1.z, x1.w,
                    x2.x, x2.y, x2.z, x2.w, x3.x, x3.y, x3.z, x3.w};
    __syncthreads();
    float4 acc = ((const float4*)b)[c4];
    const float4* w4 = (const float4*)s_w;
#pragma unroll
    for (int k = 0; k < 16; ++k) {
        float4 wv = w4[k * 16 + c4];
        FMA4(acc, xa[k], wv);
    }
    acc.x = fmaxf(acc.x, 0.f); acc.y = fmaxf(acc.y, 0.f);
    acc.z = fmaxf(acc.z, 0.f); acc.w = fmaxf(acc.w, 0.f);
    *(float4*)(h + (size_t)node * DIM + c4 * 4) = acc;
}

// ---------------- out1 = h @ lin1_w + lin1_b (once, pre-loop) ----------------
__global__ __launch_bounds__(256) void k_lin1(const float* __restrict__ h, const float* __restrict__ w,
                                              const float* __restrict__ b, float* __restrict__ out1) {
    __shared__ float s_h[64 * 68];
    int tid = threadIdx.x;
    int nb = blockIdx.x * 64;
    const float4* hp = (const float4*)(h + (size_t)nb * 64);
    for (int i = tid; i < 64 * 16; i += 256) {
        int n = i >> 4, q4 = i & 15;
        float4 v = hp[i];
        *(float4*)&s_h[n * 68 + q4 * 4] = v;
    }
    int ct = tid & 15;
    float wcol[64];
#pragma unroll
    for (int q = 0; q < 64; ++q) wcol[q] = w[q * 16 + ct];
    float bias = b[ct];
    __syncthreads();
    int ng = tid >> 4;
#pragma unroll
    for (int rep = 0; rep < 4; ++rep) {
        int nl = ng + 16 * rep;
        float acc = bias;
#pragma unroll
        for (int q4 = 0; q4 < 16; ++q4) {
            float4 hv = *(const float4*)&s_h[nl * 68 + q4 * 4];
            acc = fmaf(hv.x, wcol[4 * q4 + 0], acc);
            acc = fmaf(hv.y, wcol[4 * q4 + 1], acc);
            acc = fmaf(hv.z, wcol[4 * q4 + 2], acc);
            acc = fmaf(hv.w, wcol[4 * q4 + 3], acc);
        }
        out1[(size_t)(nb + nl) * 16 + ct] = acc;
    }
}

// ---------------- aggr v2: S-statistics gather (exact factorization) ----------------
// aggr[n][o] = inv * ( sum_k S0[k] B[k][o] + sum_i sum_k Si[k] Wi[k][o] )
// S0 = sum_e x[src], Si = sum_e a_i(e) x[src].  Edge loop: 1 load + 5 FMA per lane.
// Finish: 80 FMA/lane with reg weights; S broadcast via LDS.
__attribute__((amdgpu_waves_per_eu(3, 4)))
__global__ __launch_bounds__(256) void k_aggr(const float* __restrict__ out1, const int* __restrict__ csr_src,
                                              const float4* __restrict__ csr_ea, const int* __restrict__ row_ptr,
                                              const float* __restrict__ inv_cnt, const float* __restrict__ nn1w,
                                              const float* __restrict__ nn1b, float* __restrict__ aggr) {
    __shared__ float s_S[16 * 84];
    int tid = threadIdx.x;
    int k = tid & 15;        // component index during accumulate; output index o during finish
    int nl = tid >> 4;
    int n = blockIdx.x * 16 + nl;
    float wcb[16], wc0[16], wc1[16], wc2[16], wc3[16];
#pragma unroll
    for (int kk = 0; kk < 16; ++kk) {
        int wi = kk * 16 + k;
        wcb[kk] = nn1b[wi];
        wc0[kk] = nn1w[wi];
        wc1[kk] = nn1w[256 + wi];
        wc2[kk] = nn1w[512 + wi];
        wc3[kk] = nn1w[768 + wi];
    }
    int e0 = row_ptr[n], e1 = row_ptr[n + 1];
    float S0 = 0.f, S1 = 0.f, S2 = 0.f, S3 = 0.f, S4 = 0.f;
    if (e0 < e1) {
        // 1-deep software pipeline: prefetch next edge's src/ea/x while FMAing current
        int src = csr_src[e0];
        float4 a = csr_ea[e0];
        float xv = out1[(size_t)src * 16 + k];
        for (int e = e0; e < e1; ++e) {
            int e2 = (e + 1 < e1) ? e + 1 : e;
            int src2 = csr_src[e2];
            float4 a2 = csr_ea[e2];
            float xv2 = out1[(size_t)src2 * 16 + k];
            S0 += xv;
            S1 = fmaf(a.x, xv, S1);
            S2 = fmaf(a.y, xv, S2);
            S3 = fmaf(a.z, xv, S3);
            S4 = fmaf(a.w, xv, S4);
            xv = xv2; a = a2;
        }
    }
    s_S[nl * 84 + k]      = S0;
    s_S[nl * 84 + 16 + k] = S1;
    s_S[nl * 84 + 32 + k] = S2;
    s_S[nl * 84 + 48 + k] = S3;
    s_S[nl * 84 + 64 + k] = S4;
    __syncthreads();
    float acc = 0.f;
#pragma unroll
    for (int kk = 0; kk < 16; ++kk) {
        float sb = s_S[nl * 84 + kk];
        float s1 = s_S[nl * 84 + 16 + kk];
        float s2 = s_S[nl * 84 + 32 + kk];
        float s3 = s_S[nl * 84 + 48 + kk];
        float s4 = s_S[nl * 84 + 64 + kk];
        acc = fmaf(sb, wcb[kk], acc);
        acc = fmaf(s1, wc0[kk], acc);
        acc = fmaf(s2, wc1[kk], acc);
        acc = fmaf(s3, wc2[kk], acc);
        acc = fmaf(s4, wc3[kk], acc);
    }
    aggr[(size_t)n * 16 + k] = acc * inv_cnt[n];
}

// ---------------- node: MFMA GRU ----------------
__attribute__((amdgpu_waves_per_eu(2)))
__global__ __launch_bounds__(256) void k_node(
    float* __restrict__ out1, const float* __restrict__ aggr,
    float* __restrict__ h, const __bf16* __restrict__ Wb, const __bf16* __restrict__ rwb,
    const __bf16* __restrict__ w1b, const float* __restrict__ conv_b,
    const float* __restrict__ bih, const float* __restrict__ lin1_b)
{
    __shared__ __align__(16) __bf16 s_X[64 * 104];
    __shared__ __align__(16) __bf16 s_W[40 * 512];
    __shared__ __align__(16) __bf16 s_rw[512];
    __shared__ __align__(16) __bf16 s_w1[1024];
    int tid = threadIdx.x;
    int nb = blockIdx.x * 64;
    int lane = tid & 63, w = tid >> 6;
    int c16 = lane & 15, lq = lane >> 4;

    {
        const float4* src = (const float4*)Wb;
        float4* dst = (float4*)s_W;
#pragma unroll
        for (int i = 0; i < 10; ++i) dst[tid + 256 * i] = src[tid + 256 * i];
        if (tid < 64) ((float4*)s_rw)[tid] = ((const float4*)rwb)[tid];
        else if (tid < 192) ((float4*)s_w1)[tid - 64] = ((const float4*)w1b)[tid - 64];
    }
    {
        const float4* hsrc = (const float4*)(h + (size_t)nb * 64);
#pragma unroll
        for (int ii = 0; ii < 4; ++ii) {
            int i = tid + 256 * ii;
            float4 v = hsrc[i];
            int n = i >> 4, d4 = i & 15;
            __bf16* p = &s_X[n * 104 + 16 + d4 * 4];
            p[0] = (__bf16)v.x; p[1] = (__bf16)v.y; p[2] = (__bf16)v.z; p[3] = (__bf16)v.w;
        }
    }
    {
        float4 v = ((const float4*)(out1 + (size_t)nb * 16))[tid];
        int n = tid >> 2, k4 = tid & 3;
        __bf16* p = &s_X[n * 104 + k4 * 4];
        p[0] = (__bf16)v.x; p[1] = (__bf16)v.y; p[2] = (__bf16)v.z; p[3] = (__bf16)v.w;
        int c2 = (tid & 3) * 6;
#pragma unroll
        for (int q = 0; q < 6; ++q) {
            int col = 80 + c2 + q;
            s_X[n * 104 + col] = (col == 80) ? (__bf16)1.0f : (__bf16)0.0f;
        }
    }
    __syncthreads();

    // o2 = out1 @ root_w + aggr + conv_b
    f32x4 co2;
    {
        float cb = conv_b[c16];
#pragma unroll
        for (int jr = 0; jr < 4; ++jr) {
            int node = nb + w * 16 + 4 * lq + jr;
            co2[jr] = aggr[(size_t)node * 16 + c16] + cb;
        }
        bf16x8 a0 = *(const bf16x8*)&s_X[(w * 16 + c16) * 104 + lq * 8];
        bf16x8 brw = *(const bf16x8*)&s_rw[lane * 8];
        co2 = __builtin_amdgcn_mfma_f32_16x16x32_bf16(a0, brw, co2, 0, 0, 0);
    }
    __syncthreads();
    {
#pragma unroll
        for (int jr = 0; jr < 4; ++jr)
            s_X[(w * 16 + 4 * lq + jr) * 104 + c16] = (__bf16)co2[jr];
    }
    __syncthreads();

    // gates GEMM
    f32x4 acc[12], ani4[4];
#pragma unroll
    for (int i = 0; i < 12; ++i) acc[i] = (f32x4){0.f, 0.f, 0.f, 0.f};
#pragma unroll
    for (int i = 0; i < 4; ++i) ani4[i] = (f32x4){0.f, 0.f, 0.f, 0.f};
    bf16x8 af[3];
#pragma unroll
    for (int kk = 0; kk < 3; ++kk)
        af[kk] = *(const bf16x8*)&s_X[(w * 16 + c16) * 104 + kk * 32 + lq * 8];
#pragma unroll
    for (int ct = 0; ct < 12; ++ct) {
#pragma unroll
        for (int kk = 0; kk < 3; ++kk) {
            bf16x8 bf = *(const bf16x8*)&s_W[(ct * 3 + kk) * 512 + lane * 8];
            acc[ct] = __builtin_amdgcn_mfma_f32_16x16x32_bf16(af[kk], bf, acc[ct], 0, 0, 0);
        }
    }
#pragma unroll
    for (int ct8 = 0; ct8 < 4; ++ct8) {
        bf16x8 bf = *(const bf16x8*)&s_W[(36 + ct8) * 512 + lane * 8];
        ani4[ct8] = __builtin_amdgcn_mfma_f32_16x16x32_bf16(af[0], bf, ani4[ct8], 0, 0, 0);
    }

    // epilogue
    float hn[4][4];
#pragma unroll
    for (int ct = 0; ct < 4; ++ct) {
        float bni = bih[128 + ct * 16 + c16];
#pragma unroll
        for (int jr = 0; jr < 4; ++jr) {
            int node = nb + w * 16 + 4 * lq + jr;
            float hold = h[(size_t)node * 64 + ct * 16 + c16];
            float rr = 1.f / (1.f + __expf(-acc[ct][jr]));
            float zz = 1.f / (1.f + __expf(-acc[4 + ct][jr]));
            float xx = fmaf(rr, acc[8 + ct][jr], ani4[ct][jr] + bni);
            float ax = fabsf(xx);
            float ee = __expf(-2.f * ax);
            float ncv = __builtin_copysignf((1.f - ee) / (1.f + ee), xx);
            float hv = fmaf(zz, hold - ncv, ncv);
            hn[ct][jr] = hv;
            h[(size_t)node * 64 + ct * 16 + c16] = hv;
        }
    }
    __syncthreads();
#pragma unroll
    for (int ct = 0; ct < 4; ++ct)
#pragma unroll
        for (int jr = 0; jr < 4; ++jr)
            s_X[(w * 16 + 4 * lq + jr) * 104 + 16 + ct * 16 + c16] = (__bf16)hn[ct][jr];
    __syncthreads();

    // fused lin1
    f32x4 o1acc = (f32x4){0.f, 0.f, 0.f, 0.f};
#pragma unroll
    for (int kk = 0; kk < 2; ++kk) {
        bf16x8 a = *(const bf16x8*)&s_X[(w * 16 + c16) * 104 + 16 + kk * 32 + lq * 8];
        bf16x8 b = *(const bf16x8*)&s_w1[kk * 512 + lane * 8];
        o1acc = __builtin_amdgcn_mfma_f32_16x16x32_bf16(a, b, o1acc, 0, 0, 0);
    }
    float lb = lin1_b[c16];
#pragma unroll
    for (int jr = 0; jr < 4; ++jr) {
        int node = nb + w * 16 + 4 * lq + jr;
        out1[(size_t)node * 16 + c16] = o1acc[jr] + lb;
    }
}

// ---------------- final ----------------
__global__ __launch_bounds__(256) void k_final(const float* __restrict__ h, const float* __restrict__ w2,
                                               const int* __restrict__ batch, float* __restrict__ out) {
    int i = blockIdx.x * 4 + (threadIdx.x >> 6);
    int lane = threadIdx.x & 63;
    float v = h[(size_t)i * DIM + lane] * w2[lane];
#pragma unroll
    for (int off = 32; off > 0; off >>= 1) v += __shfl_down(v, off, 64);
    if (lane == 0) atomicAdd(&out[batch[i]], v);
}

extern "C" void kernel_launch(void* const* d_in, const int* in_sizes, int n_in,
                              void* d_out, int out_size, void* d_ws, size_t ws_size,
                              hipStream_t stream) {
    const float* x        = (const float*)d_in[0];
    const float* edge_attr= (const float*)d_in[1];
    const float* lin0_w   = (const float*)d_in[2];
    const float* lin0_b   = (const float*)d_in[3];
    const float* nn1_w    = (const float*)d_in[4];
    const float* nn1_b    = (const float*)d_in[5];
    const float* root_w   = (const float*)d_in[6];
    const float* conv_b   = (const float*)d_in[7];
    const float* gru_w_ih = (const float*)d_in[8];
    const float* gru_w_hh = (const float*)d_in[9];
    const float* gru_b_ih = (const float*)d_in[10];
    const float* gru_b_hh = (const float*)d_in[11];
    const float* lin1_w   = (const float*)d_in[12];
    const float* lin1_b   = (const float*)d_in[13];
    const float* lin2_w   = (const float*)d_in[14];
    const int*   ei       = (const int*)d_in[15];
    const int*   batch    = (const int*)d_in[16];
    float* out = (float*)d_out;

    char* p = (char*)d_ws;
    float*  h       = (float*)p;            p += (size_t)N_NODES * DIM * 4;
    float*  out1    = (float*)p;            p += (size_t)N_NODES * DNN * 4;
    float*  aggr    = (float*)p;            p += (size_t)N_NODES * DNN * 4;
    float4* csr_ea  = (float4*)p;           p += (size_t)N_EDGES * 16;
    __bf16* Wb      = (__bf16*)p;           p += 4 * 40 * 512 * 2;
    __bf16* rwb     = (__bf16*)p;           p += 512 * 2;
    __bf16* w1b     = (__bf16*)p;           p += 1024 * 2;
    int*    cnt     = (int*)p;              p += (size_t)N_NODES * 4;
    float*  inv_cnt = (float*)p;            p += (size_t)N_NODES * 4;
    int*    row_ptr = (int*)p;              p += (size_t)(N_NODES + 16) * 4;
    int*    cursor  = (int*)p;              p += (size_t)N_NODES * 4;
    int*    excl    = (int*)p;              p += (size_t)N_NODES * 4;
    int*    bsum    = (int*)p;              p += 512 * 4;
    int*    boff    = (int*)p;              p += 512 * 4;
    int*    csr_src = (int*)p;              p += (size_t)N_EDGES * 4;

    hipMemsetAsync(d_out, 0, (size_t)NG * 4, stream);
    hipMemsetAsync(cnt, 0, (size_t)N_NODES * 4, stream);
    k_prep<<<326, 256, 0, stream>>>(gru_w_ih, gru_w_hh, root_w, lin1_w, gru_b_ih, gru_b_hh,
                                    Wb, rwb, w1b);
    k_degree<<<N_EDGES / 256, 256, 0, stream>>>(ei, cnt);
    k_scanA<<<N_NODES / 256, 256, 0, stream>>>(cnt, excl, bsum);
    k_scanB<<<1, 256, 0, stream>>>(bsum, boff);
    k_scanC<<<N_NODES / 256, 256, 0, stream>>>(excl, boff, row_ptr, cursor);
    k_scatter<<<N_EDGES / 256, 256, 0, stream>>>(ei, edge_attr, cursor, csr_src, csr_ea);
    k_invcnt<<<N_NODES / 256, 256, 0, stream>>>(cnt, inv_cnt);
    k_init<<<N_NODES / 16, 256, 0, stream>>>(x, lin0_w, lin0_b, h);
    k_lin1<<<N_NODES / 64, 256, 0, stream>>>(h, lin1_w, lin1_b, out1);

    for (int it = 0; it < N_ITERS; ++it) {
        int j = it >> 1;   // GRU index (NL2 = 2)
        k_aggr<<<N_NODES / 16, 256, 0, stream>>>(out1, csr_src, csr_ea, row_ptr, inv_cnt,
                                                 nn1_w, nn1_b, aggr);
        k_node<<<N_NODES / 64, 256, 0, stream>>>(out1, aggr, h,
                                                 Wb + (size_t)j * 40 * 512, rwb, w1b,
                                                 conv_b, gru_b_ih + (size_t)j * 192, lin1_b);
    }
    k_final<<<N_NODES / 4, 256, 0, stream>>>(h, lin2_w, batch, out);
}

// Round 11
// 748.305 us; speedup vs baseline: 1.1798x; 1.1049x over previous
//
#include <hip/hip_runtime.h>
#include <hip/hip_bf16.h>

#define N_NODES 131072
#define N_EDGES 524288
#define F_IN 16
#define DIM 64
#define DNN 16
#define BK 4
#define NG 8192
#define N_ITERS 8   // NL1*NL2

typedef __bf16 bf16x8 __attribute__((ext_vector_type(8)));
typedef float f32x4 __attribute__((ext_vector_type(4)));

#define FMA4(A_, S_, W_) { (A_).x = fmaf((S_), (W_).x, (A_).x); (A_).y = fmaf((S_), (W_).y, (A_).y); \
                           (A_).z = fmaf((S_), (W_).z, (A_).z); (A_).w = fmaf((S_), (W_).w, (A_).w); }

// ---------------- degree (int) ----------------
__global__ __launch_bounds__(256) void k_degree(const int* __restrict__ ei, int* __restrict__ cnt) {
    int e = blockIdx.x * 256 + threadIdx.x;
    atomicAdd(&cnt[ei[N_EDGES + e]], 1);
}

__global__ __launch_bounds__(256) void k_invcnt(const int* __restrict__ cnt, float* __restrict__ inv) {
    int i = blockIdx.x * 256 + threadIdx.x;
    inv[i] = 1.0f / (float)max(cnt[i], 1);
}

// ---------------- CSR scan ----------------
__global__ __launch_bounds__(256) void k_scanA(const int* __restrict__ cnt, int* __restrict__ excl,
                                               int* __restrict__ bsum) {
    __shared__ int a[256], b[256];
    int t = threadIdx.x, gid = blockIdx.x * 256 + t;
    int c = cnt[gid];
    a[t] = c; __syncthreads();
    int *s = a, *d = b;
#pragma unroll
    for (int off = 1; off < 256; off <<= 1) {
        d[t] = s[t] + (t >= off ? s[t - off] : 0);
        __syncthreads();
        int* tmp = s; s = d; d = tmp;
    }
    excl[gid] = s[t] - c;
    if (t == 255) bsum[blockIdx.x] = s[255];
}

__global__ __launch_bounds__(256) void k_scanB(const int* __restrict__ bsum, int* __restrict__ boff) {
    __shared__ int a[512], b[512];
    int t = threadIdx.x;
    a[t] = bsum[t]; a[t + 256] = bsum[t + 256];
    __syncthreads();
    int *s = a, *d = b;
#pragma unroll
    for (int off = 1; off < 512; off <<= 1) {
        d[t] = s[t] + (t >= off ? s[t - off] : 0);
        int i2 = t + 256;
        d[i2] = s[i2] + (i2 >= off ? s[i2 - off] : 0);
        __syncthreads();
        int* tmp = s; s = d; d = tmp;
    }
    boff[t] = t ? s[t - 1] : 0;
    boff[t + 256] = s[t + 255];
}

__global__ __launch_bounds__(256) void k_scanC(const int* __restrict__ excl, const int* __restrict__ boff,
                                               int* __restrict__ row_ptr, int* __restrict__ cursor) {
    int gid = blockIdx.x * 256 + threadIdx.x;
    int v = excl[gid] + boff[gid >> 8];
    row_ptr[gid] = v;
    cursor[gid] = v;
    if (gid == 0) row_ptr[N_NODES] = N_EDGES;
}

__global__ __launch_bounds__(256) void k_scatter(const int* __restrict__ ei, const float* __restrict__ ea,
                                                 int* __restrict__ cursor, int* __restrict__ csr_src,
                                                 float4* __restrict__ csr_ea) {
    int e = blockIdx.x * 256 + threadIdx.x;
    int dst = ei[N_EDGES + e];
    int pos = atomicAdd(&cursor[dst], 1);
    csr_src[pos] = ei[e];
    csr_ea[pos] = ((const float4*)ea)[e];
}

// ---------------- prep: build bf16 B-fragment weight tiles ----------------
__global__ __launch_bounds__(256) void k_prep(const float* __restrict__ wih, const float* __restrict__ whh,
                                              const float* __restrict__ rw, const float* __restrict__ w1,
                                              const float* __restrict__ bih, const float* __restrict__ bhh,
                                              __bf16* __restrict__ Wb, __bf16* __restrict__ rwb,
                                              __bf16* __restrict__ w1b) {
    int idx = blockIdx.x * 256 + threadIdx.x;
    if (idx < 4 * 40 * 512) {
        int j = idx / 20480, r = idx % 20480;
        int t = r >> 9, e = r & 511;
        int jj = e & 7, c16 = (e >> 3) & 15, kq = e >> 7;
        int ct, kk; bool nih = false;
        if (t < 36) { ct = t / 3; kk = t % 3; } else { ct = 8 + (t - 36); kk = 0; nih = true; }
        int k = kk * 32 + kq * 8 + jj;
        int c = ct * 16 + c16;
        bool ngate = ct >= 8;
        float v = 0.f;
        if (nih) {
            if (k < 16) v = wih[((size_t)j * 192 + c) * 16 + k];
        } else {
            if (k < 16) v = ngate ? 0.f : wih[((size_t)j * 192 + c) * 16 + k];
            else if (k < 80) v = whh[((size_t)j * 192 + c) * 64 + (k - 16)];
            else if (k == 80) v = ngate ? bhh[j * 192 + c] : (bih[j * 192 + c] + bhh[j * 192 + c]);
        }
        Wb[idx] = (__bf16)v;
    } else if (idx < 4 * 40 * 512 + 512) {
        int e = idx - 4 * 40 * 512;
        int jj = e & 7, c16 = (e >> 3) & 15, kq = e >> 7;
        int k = kq * 8 + jj;
        rwb[e] = (__bf16)((k < 16) ? rw[k * 16 + c16] : 0.f);
    } else if (idx < 4 * 40 * 512 + 512 + 1024) {
        int e = idx - (4 * 40 * 512 + 512);
        int t2 = e >> 9, ee = e & 511;
        int jj = ee & 7, c16 = (ee >> 3) & 15, kq = ee >> 7;
        int k = t2 * 32 + kq * 8 + jj;
        w1b[e] = (__bf16)w1[k * 16 + c16];
    }
}

// ---------------- init: h = relu(x @ lin0_w + lin0_b), 4 channels/thread ----------------
__global__ __launch_bounds__(256) void k_init(const float* __restrict__ x, const float* __restrict__ w,
                                              const float* __restrict__ b, float* __restrict__ h) {
    __shared__ float s_w[F_IN * DIM];
    int tid = threadIdx.x;
    for (int i = tid; i < F_IN * DIM; i += 256) s_w[i] = w[i];
    int node = blockIdx.x * 16 + (tid >> 4);
    int c4 = tid & 15;
    const float4* xp = (const float4*)(x + (size_t)node * F_IN);
    float4 x0 = xp[0], x1 = xp[1], x2 = xp[2], x3 = xp[3];
    float xa[16] = {x0.x, x0.y, x0.z, x0.w, x1.x, x1.y, x1.z, x1.w,
                    x2.x, x2.y, x2.z, x2.w, x3.x, x3.y, x3.z, x3.w};
    __syncthreads();
    float4 acc = ((const float4*)b)[c4];
    const float4* w4 = (const float4*)s_w;
#pragma unroll
    for (int k = 0; k < 16; ++k) {
        float4 wv = w4[k * 16 + c4];
        FMA4(acc, xa[k], wv);
    }
    acc.x = fmaxf(acc.x, 0.f); acc.y = fmaxf(acc.y, 0.f);
    acc.z = fmaxf(acc.z, 0.f); acc.w = fmaxf(acc.w, 0.f);
    *(float4*)(h + (size_t)node * DIM + c4 * 4) = acc;
}

// ---------------- out1 = h @ lin1_w + lin1_b (once, pre-loop) ----------------
__global__ __launch_bounds__(256) void k_lin1(const float* __restrict__ h, const float* __restrict__ w,
                                              const float* __restrict__ b, float* __restrict__ out1) {
    __shared__ float s_h[64 * 68];
    int tid = threadIdx.x;
    int nb = blockIdx.x * 64;
    const float4* hp = (const float4*)(h + (size_t)nb * 64);
    for (int i = tid; i < 64 * 16; i += 256) {
        int n = i >> 4, q4 = i & 15;
        float4 v = hp[i];
        *(float4*)&s_h[n * 68 + q4 * 4] = v;
    }
    int ct = tid & 15;
    float wcol[64];
#pragma unroll
    for (int q = 0; q < 64; ++q) wcol[q] = w[q * 16 + ct];
    float bias = b[ct];
    __syncthreads();
    int ng = tid >> 4;
#pragma unroll
    for (int rep = 0; rep < 4; ++rep) {
        int nl = ng + 16 * rep;
        float acc = bias;
#pragma unroll
        for (int q4 = 0; q4 < 16; ++q4) {
            float4 hv = *(const float4*)&s_h[nl * 68 + q4 * 4];
            acc = fmaf(hv.x, wcol[4 * q4 + 0], acc);
            acc = fmaf(hv.y, wcol[4 * q4 + 1], acc);
            acc = fmaf(hv.z, wcol[4 * q4 + 2], acc);
            acc = fmaf(hv.w, wcol[4 * q4 + 3], acc);
        }
        out1[(size_t)(nb + nl) * 16 + ct] = acc;
    }
}

// ---------------- aggr v3: wave-per-node S-gather ----------------
// 64 lanes = 4 edge-slots x 16 components. Edge loop strides by 4 (latency/4).
// S reduced across slots via shfl_xor; finish split across slots (20 FMA/lane);
// same-wave LDS bounce redistributes S (no __syncthreads -> waves independent).
__global__ __launch_bounds__(256) void k_aggr(const float* __restrict__ out1, const int* __restrict__ csr_src,
                                              const float4* __restrict__ csr_ea, const int* __restrict__ row_ptr,
                                              const float* __restrict__ inv_cnt, const float* __restrict__ nn1w,
                                              const float* __restrict__ nn1b, float* __restrict__ aggr) {
    __shared__ float s_S[4][80];
    int tid = threadIdx.x;
    int lane = tid & 63;
    int wv = tid >> 6;             // node slot within block
    int k = lane & 15;             // component / output col
    int slot = lane >> 4;          // edge slot / kk quarter
    int n = blockIdx.x * 4 + wv;
    // weights for kk = slot*4+q, output col k
    float wcb[4], wc0[4], wc1[4], wc2[4], wc3[4];
#pragma unroll
    for (int q = 0; q < 4; ++q) {
        int wi = (slot * 4 + q) * 16 + k;
        wcb[q] = nn1b[wi];
        wc0[q] = nn1w[wi];
        wc1[q] = nn1w[256 + wi];
        wc2[q] = nn1w[512 + wi];
        wc3[q] = nn1w[768 + wi];
    }
    int e0 = row_ptr[n], e1 = row_ptr[n + 1];
    float S0 = 0.f, S1 = 0.f, S2 = 0.f, S3 = 0.f, S4 = 0.f;
    for (int e = e0 + slot; e < e1; e += 4) {
        int src = csr_src[e];
        float4 a = csr_ea[e];
        float xv = out1[(size_t)src * 16 + k];
        S0 += xv;
        S1 = fmaf(a.x, xv, S1);
        S2 = fmaf(a.y, xv, S2);
        S3 = fmaf(a.z, xv, S3);
        S4 = fmaf(a.w, xv, S4);
    }
    // butterfly reduce across slots (every lane ends with the total)
    S0 += __shfl_xor(S0, 16, 64); S0 += __shfl_xor(S0, 32, 64);
    S1 += __shfl_xor(S1, 16, 64); S1 += __shfl_xor(S1, 32, 64);
    S2 += __shfl_xor(S2, 16, 64); S2 += __shfl_xor(S2, 32, 64);
    S3 += __shfl_xor(S3, 16, 64); S3 += __shfl_xor(S3, 32, 64);
    S4 += __shfl_xor(S4, 16, 64); S4 += __shfl_xor(S4, 32, 64);
    if (slot == 0) {
        s_S[wv][k]      = S0;
        s_S[wv][16 + k] = S1;
        s_S[wv][32 + k] = S2;
        s_S[wv][48 + k] = S3;
        s_S[wv][64 + k] = S4;
    }
    asm volatile("" ::: "memory");   // keep ds_write before ds_read (same wave -> in-order DS pipe)
    float part = 0.f;
#pragma unroll
    for (int q = 0; q < 4; ++q) {
        int kk = slot * 4 + q;
        part = fmaf(s_S[wv][kk],      wcb[q], part);
        part = fmaf(s_S[wv][16 + kk], wc0[q], part);
        part = fmaf(s_S[wv][32 + kk], wc1[q], part);
        part = fmaf(s_S[wv][48 + kk], wc2[q], part);
        part = fmaf(s_S[wv][64 + kk], wc3[q], part);
    }
    part += __shfl_xor(part, 16, 64);
    part += __shfl_xor(part, 32, 64);
    if (slot == 0) aggr[(size_t)n * 16 + k] = part * inv_cnt[n];
}

// ---------------- node: MFMA GRU ----------------
__attribute__((amdgpu_waves_per_eu(2)))
__global__ __launch_bounds__(256) void k_node(
    float* __restrict__ out1, const float* __restrict__ aggr,
    float* __restrict__ h, const __bf16* __restrict__ Wb, const __bf16* __restrict__ rwb,
    const __bf16* __restrict__ w1b, const float* __restrict__ conv_b,
    const float* __restrict__ bih, const float* __restrict__ lin1_b)
{
    __shared__ __align__(16) __bf16 s_X[64 * 104];
    __shared__ __align__(16) __bf16 s_W[40 * 512];
    __shared__ __align__(16) __bf16 s_rw[512];
    __shared__ __align__(16) __bf16 s_w1[1024];
    int tid = threadIdx.x;
    int nb = blockIdx.x * 64;
    int lane = tid & 63, w = tid >> 6;
    int c16 = lane & 15, lq = lane >> 4;

    {
        const float4* src = (const float4*)Wb;
        float4* dst = (float4*)s_W;
#pragma unroll
        for (int i = 0; i < 10; ++i) dst[tid + 256 * i] = src[tid + 256 * i];
        if (tid < 64) ((float4*)s_rw)[tid] = ((const float4*)rwb)[tid];
        else if (tid < 192) ((float4*)s_w1)[tid - 64] = ((const float4*)w1b)[tid - 64];
    }
    {
        const float4* hsrc = (const float4*)(h + (size_t)nb * 64);
#pragma unroll
        for (int ii = 0; ii < 4; ++ii) {
            int i = tid + 256 * ii;
            float4 v = hsrc[i];
            int n = i >> 4, d4 = i & 15;
            __bf16* p = &s_X[n * 104 + 16 + d4 * 4];
            p[0] = (__bf16)v.x; p[1] = (__bf16)v.y; p[2] = (__bf16)v.z; p[3] = (__bf16)v.w;
        }
    }
    {
        float4 v = ((const float4*)(out1 + (size_t)nb * 16))[tid];
        int n = tid >> 2, k4 = tid & 3;
        __bf16* p = &s_X[n * 104 + k4 * 4];
        p[0] = (__bf16)v.x; p[1] = (__bf16)v.y; p[2] = (__bf16)v.z; p[3] = (__bf16)v.w;
        int c2 = (tid & 3) * 6;
#pragma unroll
        for (int q = 0; q < 6; ++q) {
            int col = 80 + c2 + q;
            s_X[n * 104 + col] = (col == 80) ? (__bf16)1.0f : (__bf16)0.0f;
        }
    }
    __syncthreads();

    // o2 = out1 @ root_w + aggr + conv_b
    f32x4 co2;
    {
        float cb = conv_b[c16];
#pragma unroll
        for (int jr = 0; jr < 4; ++jr) {
            int node = nb + w * 16 + 4 * lq + jr;
            co2[jr] = aggr[(size_t)node * 16 + c16] + cb;
        }
        bf16x8 a0 = *(const bf16x8*)&s_X[(w * 16 + c16) * 104 + lq * 8];
        bf16x8 brw = *(const bf16x8*)&s_rw[lane * 8];
        co2 = __builtin_amdgcn_mfma_f32_16x16x32_bf16(a0, brw, co2, 0, 0, 0);
    }
    __syncthreads();
    {
#pragma unroll
        for (int jr = 0; jr < 4; ++jr)
            s_X[(w * 16 + 4 * lq + jr) * 104 + c16] = (__bf16)co2[jr];
    }
    __syncthreads();

    // gates GEMM
    f32x4 acc[12], ani4[4];
#pragma unroll
    for (int i = 0; i < 12; ++i) acc[i] = (f32x4){0.f, 0.f, 0.f, 0.f};
#pragma unroll
    for (int i = 0; i < 4; ++i) ani4[i] = (f32x4){0.f, 0.f, 0.f, 0.f};
    bf16x8 af[3];
#pragma unroll
    for (int kk = 0; kk < 3; ++kk)
        af[kk] = *(const bf16x8*)&s_X[(w * 16 + c16) * 104 + kk * 32 + lq * 8];
#pragma unroll
    for (int ct = 0; ct < 12; ++ct) {
#pragma unroll
        for (int kk = 0; kk < 3; ++kk) {
            bf16x8 bf = *(const bf16x8*)&s_W[(ct * 3 + kk) * 512 + lane * 8];
            acc[ct] = __builtin_amdgcn_mfma_f32_16x16x32_bf16(af[kk], bf, acc[ct], 0, 0, 0);
        }
    }
#pragma unroll
    for (int ct8 = 0; ct8 < 4; ++ct8) {
        bf16x8 bf = *(const bf16x8*)&s_W[(36 + ct8) * 512 + lane * 8];
        ani4[ct8] = __builtin_amdgcn_mfma_f32_16x16x32_bf16(af[0], bf, ani4[ct8], 0, 0, 0);
    }

    // epilogue
    float hn[4][4];
#pragma unroll
    for (int ct = 0; ct < 4; ++ct) {
        float bni = bih[128 + ct * 16 + c16];
#pragma unroll
        for (int jr = 0; jr < 4; ++jr) {
            int node = nb + w * 16 + 4 * lq + jr;
            float hold = h[(size_t)node * 64 + ct * 16 + c16];
            float rr = 1.f / (1.f + __expf(-acc[ct][jr]));
            float zz = 1.f / (1.f + __expf(-acc[4 + ct][jr]));
            float xx = fmaf(rr, acc[8 + ct][jr], ani4[ct][jr] + bni);
            float ax = fabsf(xx);
            float ee = __expf(-2.f * ax);
            float ncv = __builtin_copysignf((1.f - ee) / (1.f + ee), xx);
            float hv = fmaf(zz, hold - ncv, ncv);
            hn[ct][jr] = hv;
            h[(size_t)node * 64 + ct * 16 + c16] = hv;
        }
    }
    __syncthreads();
#pragma unroll
    for (int ct = 0; ct < 4; ++ct)
#pragma unroll
        for (int jr = 0; jr < 4; ++jr)
            s_X[(w * 16 + 4 * lq + jr) * 104 + 16 + ct * 16 + c16] = (__bf16)hn[ct][jr];
    __syncthreads();

    // fused lin1
    f32x4 o1acc = (f32x4){0.f, 0.f, 0.f, 0.f};
#pragma unroll
    for (int kk = 0; kk < 2; ++kk) {
        bf16x8 a = *(const bf16x8*)&s_X[(w * 16 + c16) * 104 + 16 + kk * 32 + lq * 8];
        bf16x8 b = *(const bf16x8*)&s_w1[kk * 512 + lane * 8];
        o1acc = __builtin_amdgcn_mfma_f32_16x16x32_bf16(a, b, o1acc, 0, 0, 0);
    }
    float lb = lin1_b[c16];
#pragma unroll
    for (int jr = 0; jr < 4; ++jr) {
        int node = nb + w * 16 + 4 * lq + jr;
        out1[(size_t)node * 16 + c16] = o1acc[jr] + lb;
    }
}

// ---------------- final ----------------
__global__ __launch_bounds__(256) void k_final(const float* __restrict__ h, const float* __restrict__ w2,
                                               const int* __restrict__ batch, float* __restrict__ out) {
    int i = blockIdx.x * 4 + (threadIdx.x >> 6);
    int lane = threadIdx.x & 63;
    float v = h[(size_t)i * DIM + lane] * w2[lane];
#pragma unroll
    for (int off = 32; off > 0; off >>= 1) v += __shfl_down(v, off, 64);
    if (lane == 0) atomicAdd(&out[batch[i]], v);
}

extern "C" void kernel_launch(void* const* d_in, const int* in_sizes, int n_in,
                              void* d_out, int out_size, void* d_ws, size_t ws_size,
                              hipStream_t stream) {
    const float* x        = (const float*)d_in[0];
    const float* edge_attr= (const float*)d_in[1];
    const float* lin0_w   = (const float*)d_in[2];
    const float* lin0_b   = (const float*)d_in[3];
    const float* nn1_w    = (const float*)d_in[4];
    const float* nn1_b    = (const float*)d_in[5];
    const float* root_w   = (const float*)d_in[6];
    const float* conv_b   = (const float*)d_in[7];
    const float* gru_w_ih = (const float*)d_in[8];
    const float* gru_w_hh = (const float*)d_in[9];
    const float* gru_b_ih = (const float*)d_in[10];
    const float* gru_b_hh = (const float*)d_in[11];
    const float* lin1_w   = (const float*)d_in[12];
    const float* lin1_b   = (const float*)d_in[13];
    const float* lin2_w   = (const float*)d_in[14];
    const int*   ei       = (const int*)d_in[15];
    const int*   batch    = (const int*)d_in[16];
    float* out = (float*)d_out;

    char* p = (char*)d_ws;
    float*  h       = (float*)p;            p += (size_t)N_NODES * DIM * 4;
    float*  out1    = (float*)p;            p += (size_t)N_NODES * DNN * 4;
    float*  aggr    = (float*)p;            p += (size_t)N_NODES * DNN * 4;
    float4* csr_ea  = (float4*)p;           p += (size_t)N_EDGES * 16;
    __bf16* Wb      = (__bf16*)p;           p += 4 * 40 * 512 * 2;
    __bf16* rwb     = (__bf16*)p;           p += 512 * 2;
    __bf16* w1b     = (__bf16*)p;           p += 1024 * 2;
    int*    cnt     = (int*)p;              p += (size_t)N_NODES * 4;
    float*  inv_cnt = (float*)p;            p += (size_t)N_NODES * 4;
    int*    row_ptr = (int*)p;              p += (size_t)(N_NODES + 16) * 4;
    int*    cursor  = (int*)p;              p += (size_t)N_NODES * 4;
    int*    excl    = (int*)p;              p += (size_t)N_NODES * 4;
    int*    bsum    = (int*)p;              p += 512 * 4;
    int*    boff    = (int*)p;              p += 512 * 4;
    int*    csr_src = (int*)p;              p += (size_t)N_EDGES * 4;

    hipMemsetAsync(d_out, 0, (size_t)NG * 4, stream);
    hipMemsetAsync(cnt, 0, (size_t)N_NODES * 4, stream);
    k_prep<<<326, 256, 0, stream>>>(gru_w_ih, gru_w_hh, root_w, lin1_w, gru_b_ih, gru_b_hh,
                                    Wb, rwb, w1b);
    k_degree<<<N_EDGES / 256, 256, 0, stream>>>(ei, cnt);
    k_scanA<<<N_NODES / 256, 256, 0, stream>>>(cnt, excl, bsum);
    k_scanB<<<1, 256, 0, stream>>>(bsum, boff);
    k_scanC<<<N_NODES / 256, 256, 0, stream>>>(excl, boff, row_ptr, cursor);
    k_scatter<<<N_EDGES / 256, 256, 0, stream>>>(ei, edge_attr, cursor, csr_src, csr_ea);
    k_invcnt<<<N_NODES / 256, 256, 0, stream>>>(cnt, inv_cnt);
    k_init<<<N_NODES / 16, 256, 0, stream>>>(x, lin0_w, lin0_b, h);
    k_lin1<<<N_NODES / 64, 256, 0, stream>>>(h, lin1_w, lin1_b, out1);

    for (int it = 0; it < N_ITERS; ++it) {
        int j = it >> 1;   // GRU index (NL2 = 2)
        k_aggr<<<N_NODES / 4, 256, 0, stream>>>(out1, csr_src, csr_ea, row_ptr, inv_cnt,
                                                nn1_w, nn1_b, aggr);
        k_node<<<N_NODES / 64, 256, 0, stream>>>(out1, aggr, h,
                                                 Wb + (size_t)j * 40 * 512, rwb, w1b,
                                                 conv_b, gru_b_ih + (size_t)j * 192, lin1_b);
    }
    k_final<<<N_NODES / 4, 256, 0, stream>>>(h, lin2_w, batch, out);
}